// Round 1
// baseline (47.032 us; speedup 1.0000x reference)
//
#include <hip/hip_runtime.h>

// Cochlea: compress (piecewise-linear) + first-order IIR along T + ReLU.
// B=32, T=4096, F=64, alpha=0.9.
//
// Strategy: chunked scan with warm-up truncation. The IIR is linear with
// decay 0.9^k, so a chunk started K=96 steps early from y=0 matches the
// exact scan to within 6 * 0.9^96 ~= 2.4e-4 (threshold is 2.78e-2).
// One thread per (b, f, chunk): 32*64*32 = 65536 threads = 1024 waves,
// 4 waves/CU. Lanes of a wave share (b,chunk) and span f=0..63, so every
// t-step is one coalesced 256B row read/write.

namespace {
constexpr int kB  = 32;
constexpr int kT  = 4096;
constexpr int kF  = 64;
constexpr int kNC = 32;           // chunks along T
constexpr int kL  = kT / kNC;     // 128 outputs per thread
constexpr int kK  = 96;           // warm-up steps (0.9^96 ~= 4e-5)
constexpr float kAlpha = 0.9f;
constexpr float kOneMinusAlpha = 1.0f - kAlpha;
}

__global__ __launch_bounds__(256) void cochlea_kernel(
    const float* __restrict__ spec,
    const float* __restrict__ ftune,
    const float* __restrict__ thr_p,
    const float* __restrict__ ratio_p,
    float* __restrict__ out)
{
    const int g = blockIdx.x * 256 + threadIdx.x;
    const int f = g & (kF - 1);
    const int c = (g >> 6) & (kNC - 1);
    const int b = g >> 11;            // g / (kF * kNC)

    const float ft    = ftune[f];
    const float thr   = thr_p[0];     // uniform -> s_load
    const float ratio = ratio_p[0];

    const size_t base = ((size_t)b * kT + (size_t)c * kL) * kF + f;
    const float* p;
    float* q = out + base;
    float y = 0.0f;
    int main_from = 0;

    if (c == 0) {
        // Exact: first row is compressed[b,0,f] directly (no IIR step).
        float tuned = spec[base] * ft;
        float cv = fmaf(tuned - thr, ratio, thr);
        y = (tuned > thr) ? cv : tuned;
        q[0] = fmaxf(y, 0.0f);
        p = spec + base + kF;
        q += kF;
        main_from = 1;
    } else {
        // Warm-up: run the recurrence K steps before the chunk, y0 = 0.
        p = spec + base - (size_t)kK * kF;
        #pragma unroll 8
        for (int k = 0; k < kK; ++k) {
            float tuned = p[0] * ft; p += kF;
            float cv = fmaf(tuned - thr, ratio, thr);
            float v = (tuned > thr) ? cv : tuned;
            y = fmaf(kAlpha, y, kOneMinusAlpha * v);
        }
    }

    #pragma unroll 8
    for (int k = main_from; k < kL; ++k) {
        float tuned = p[0] * ft; p += kF;
        float cv = fmaf(tuned - thr, ratio, thr);
        float v = (tuned > thr) ? cv : tuned;
        y = fmaf(kAlpha, y, kOneMinusAlpha * v);
        *q = fmaxf(y, 0.0f); q += kF;
    }
}

extern "C" void kernel_launch(void* const* d_in, const int* in_sizes, int n_in,
                              void* d_out, int out_size, void* d_ws, size_t ws_size,
                              hipStream_t stream) {
    const float* spec  = (const float*)d_in[0];
    const float* ftune = (const float*)d_in[1];
    const float* thr   = (const float*)d_in[2];
    const float* ratio = (const float*)d_in[3];
    float* out = (float*)d_out;

    const int total_threads = kB * kF * kNC;   // 65536
    dim3 grid(total_threads / 256), block(256);
    cochlea_kernel<<<grid, block, 0, stream>>>(spec, ftune, thr, ratio, out);
}

// Round 2
// 24.677 us; speedup vs baseline: 1.9059x; 1.9059x over previous
//
#include <hip/hip_runtime.h>

// Cochlea: per-f compress + first-order IIR (alpha=0.9) along T + ReLU.
// B=32, T=4096, F=64.
//
// Chunked scan with warm-up truncation (linear recurrence, carry decays as
// 0.9^k). NC=128 chunks of L=32; K=72 warm-up steps (0.9^72*|y| ~ 5e-4,
// threshold 2.78e-2). Chunks whose warm-up would cross t=0 instead run the
// EXACT recurrence from t=0 (y0 = compressed[t=0]) -- no truncation there.
//
// Round-1 post-mortem: latency-bound (VALUBusy 3.9%, HBM 11%, occ 7.7%) --
// per-thread 4B loads were serialized. Fix: float4 per thread (4 IIR chains,
// 16B loads) + explicit 8-deep load staging into a statically-indexed
// register array so 128B/lane stays in flight.

namespace {
constexpr int kB   = 32;
constexpr int kT   = 4096;
constexpr int kF4  = 16;          // F=64 floats = 16 float4 per row
constexpr int kNC  = 128;         // chunks along T
constexpr int kL   = kT / kNC;    // 32 outputs per thread
constexpr int kK   = 72;          // warm-up steps
constexpr int kU   = 8;           // load-staging depth
constexpr float kA   = 0.9f;
constexpr float kOmA = 1.0f - kA;
}

__global__ __launch_bounds__(256) void cochlea_kernel(
    const float4* __restrict__ spec,
    const float4* __restrict__ ftune,
    const float* __restrict__ thr_p,
    const float* __restrict__ ratio_p,
    float4* __restrict__ out)
{
    const int g  = blockIdx.x * 256 + threadIdx.x;
    const int f4 = g & (kF4 - 1);
    const int c  = (g >> 4) & (kNC - 1);
    const int b  = g >> 11;

    const float thr   = thr_p[0];
    const float ratio = ratio_p[0];
    const float4 ftv  = ftune[f4];
    const float ft[4] = {ftv.x, ftv.y, ftv.z, ftv.w};

    const float4* sp = spec + (size_t)b * kT * kF4 + f4;
    float4*       op = out  + (size_t)b * kT * kF4 + f4;

    const int tstart = c * kL;
    const int tend   = tstart + kL;

    float y[4];
    int t;

    auto compress = [&](const float4& xv, float* v) {
        const float x[4] = {xv.x, xv.y, xv.z, xv.w};
        #pragma unroll
        for (int i = 0; i < 4; ++i) {
            float tuned = x[i] * ft[i];
            float cv    = fmaf(tuned - thr, ratio, thr);
            v[i] = (tuned > thr) ? cv : tuned;
        }
    };

    if (tstart - kK <= 0) {
        // Exact path: y(0) = compressed(t=0), recurrence from t=1.
        compress(sp[0], y);
        if (c == 0) {
            float4 o = {fmaxf(y[0], 0.f), fmaxf(y[1], 0.f),
                        fmaxf(y[2], 0.f), fmaxf(y[3], 0.f)};
            op[0] = o;
        }
        t = 1;
    } else {
        y[0] = y[1] = y[2] = y[3] = 0.f;
        t = tstart - kK;
    }

    // ---- warm-up: [t, tstart), no stores ----
    for (; t + kU <= tstart; t += kU) {
        float4 xv[kU];
        #pragma unroll
        for (int j = 0; j < kU; ++j) xv[j] = sp[(size_t)(t + j) * kF4];
        #pragma unroll
        for (int j = 0; j < kU; ++j) {
            float v[4]; compress(xv[j], v);
            #pragma unroll
            for (int i = 0; i < 4; ++i) y[i] = fmaf(kA, y[i], kOmA * v[i]);
        }
    }
    for (; t < tstart; ++t) {
        float v[4]; compress(sp[(size_t)t * kF4], v);
        #pragma unroll
        for (int i = 0; i < 4; ++i) y[i] = fmaf(kA, y[i], kOmA * v[i]);
    }

    // ---- main: [t, tend), with stores ----
    for (; t + kU <= tend; t += kU) {
        float4 xv[kU];
        #pragma unroll
        for (int j = 0; j < kU; ++j) xv[j] = sp[(size_t)(t + j) * kF4];
        #pragma unroll
        for (int j = 0; j < kU; ++j) {
            float v[4]; compress(xv[j], v);
            float4 o;
            y[0] = fmaf(kA, y[0], kOmA * v[0]); o.x = fmaxf(y[0], 0.f);
            y[1] = fmaf(kA, y[1], kOmA * v[1]); o.y = fmaxf(y[1], 0.f);
            y[2] = fmaf(kA, y[2], kOmA * v[2]); o.z = fmaxf(y[2], 0.f);
            y[3] = fmaf(kA, y[3], kOmA * v[3]); o.w = fmaxf(y[3], 0.f);
            op[(size_t)(t + j) * kF4] = o;
        }
    }
    for (; t < tend; ++t) {
        float v[4]; compress(sp[(size_t)t * kF4], v);
        float4 o;
        y[0] = fmaf(kA, y[0], kOmA * v[0]); o.x = fmaxf(y[0], 0.f);
        y[1] = fmaf(kA, y[1], kOmA * v[1]); o.y = fmaxf(y[1], 0.f);
        y[2] = fmaf(kA, y[2], kOmA * v[2]); o.z = fmaxf(y[2], 0.f);
        y[3] = fmaf(kA, y[3], kOmA * v[3]); o.w = fmaxf(y[3], 0.f);
        op[(size_t)t * kF4] = o;
    }
}

extern "C" void kernel_launch(void* const* d_in, const int* in_sizes, int n_in,
                              void* d_out, int out_size, void* d_ws, size_t ws_size,
                              hipStream_t stream) {
    const float4* spec  = (const float4*)d_in[0];
    const float4* ftune = (const float4*)d_in[1];
    const float*  thr   = (const float*)d_in[2];
    const float*  ratio = (const float*)d_in[3];
    float4* out = (float4*)d_out;

    const int total_threads = kB * kF4 * kNC;   // 65536
    dim3 grid(total_threads / 256), block(256);
    cochlea_kernel<<<grid, block, 0, stream>>>(spec, ftune, thr, ratio, out);
}

// Round 3
// 24.266 us; speedup vs baseline: 1.9382x; 1.0169x over previous
//
#include <hip/hip_runtime.h>

// Cochlea: per-f compress + first-order IIR (alpha=0.9) along T + ReLU.
// B=32, T=4096, F=64.
//
// Chunked scan with warm-up truncation. NC=256 chunks of L=16; K=64 warm-up
// (0.9^64 * |y|max ~ 3.5e-3 << 2.78e-2 threshold). Chunks whose warm-up
// would cross t=0 run the exact recurrence from t=0.
//
// Round-2 post-mortem: 1 wave/SIMD -> latency-exposed (occ 8%, VALU 4%).
// Fix: float2 per thread + NC=256 -> 262144 threads = 4 waves/SIMD; 8-deep
// load staging per wave -> 4 independent load batches in flight per SIMD.
// Non-temporal output stores keep the 33MB write stream out of L2 so
// warm-up re-reads of spec stay L2-resident.

typedef float vf2 __attribute__((ext_vector_type(2)));

namespace {
constexpr int kB   = 32;
constexpr int kT   = 4096;
constexpr int kF2  = 32;          // F=64 floats = 32 float2 per row
constexpr int kNC  = 256;         // chunks along T
constexpr int kL   = kT / kNC;    // 16 outputs per thread
constexpr int kK   = 64;          // warm-up steps
constexpr int kU   = 8;           // load-staging depth
constexpr float kA   = 0.9f;
constexpr float kOmA = 1.0f - kA;
}

__global__ __launch_bounds__(256) void cochlea_kernel(
    const vf2* __restrict__ spec,
    const vf2* __restrict__ ftune,
    const float* __restrict__ thr_p,
    const float* __restrict__ ratio_p,
    vf2* __restrict__ out)
{
    const int g  = blockIdx.x * 256 + threadIdx.x;
    const int f2 = g & (kF2 - 1);
    const int c  = (g >> 5) & (kNC - 1);
    const int b  = g >> 13;

    const float thr   = thr_p[0];
    const float ratio = ratio_p[0];
    const vf2 ft = ftune[f2];

    const vf2* sp = spec + (size_t)b * kT * kF2 + f2;
    vf2*       op = out  + (size_t)b * kT * kF2 + f2;

    const int tstart = c * kL;
    const int tend   = tstart + kL;

    float y0, y1;
    int t;

    auto comp = [&](vf2 xv, float& v0, float& v1) {
        float t0 = xv.x * ft.x;
        float t1 = xv.y * ft.y;
        float c0 = fmaf(t0 - thr, ratio, thr);
        float c1 = fmaf(t1 - thr, ratio, thr);
        v0 = (t0 > thr) ? c0 : t0;
        v1 = (t1 > thr) ? c1 : t1;
    };

    if (tstart - kK <= 0) {
        // Exact path: y(0) = compressed(t=0), recurrence from t=1.
        comp(sp[0], y0, y1);
        if (c == 0) {
            vf2 o = {fmaxf(y0, 0.f), fmaxf(y1, 0.f)};
            __builtin_nontemporal_store(o, op);
        }
        t = 1;
    } else {
        y0 = y1 = 0.f;
        t = tstart - kK;
    }

    // ---- warm-up: [t, tstart), no stores ----
    for (; t + kU <= tstart; t += kU) {
        vf2 xv[kU];
        #pragma unroll
        for (int j = 0; j < kU; ++j) xv[j] = sp[(size_t)(t + j) * kF2];
        #pragma unroll
        for (int j = 0; j < kU; ++j) {
            float v0, v1; comp(xv[j], v0, v1);
            y0 = fmaf(kA, y0, kOmA * v0);
            y1 = fmaf(kA, y1, kOmA * v1);
        }
    }
    for (; t < tstart; ++t) {
        float v0, v1; comp(sp[(size_t)t * kF2], v0, v1);
        y0 = fmaf(kA, y0, kOmA * v0);
        y1 = fmaf(kA, y1, kOmA * v1);
    }

    // ---- main: [t, tend), with stores ----
    for (; t + kU <= tend; t += kU) {
        vf2 xv[kU];
        #pragma unroll
        for (int j = 0; j < kU; ++j) xv[j] = sp[(size_t)(t + j) * kF2];
        #pragma unroll
        for (int j = 0; j < kU; ++j) {
            float v0, v1; comp(xv[j], v0, v1);
            y0 = fmaf(kA, y0, kOmA * v0);
            y1 = fmaf(kA, y1, kOmA * v1);
            vf2 o = {fmaxf(y0, 0.f), fmaxf(y1, 0.f)};
            __builtin_nontemporal_store(o, op + (size_t)(t + j) * kF2);
        }
    }
    for (; t < tend; ++t) {
        float v0, v1; comp(sp[(size_t)t * kF2], v0, v1);
        y0 = fmaf(kA, y0, kOmA * v0);
        y1 = fmaf(kA, y1, kOmA * v1);
        vf2 o = {fmaxf(y0, 0.f), fmaxf(y1, 0.f)};
        __builtin_nontemporal_store(o, op + (size_t)t * kF2);
    }
}

extern "C" void kernel_launch(void* const* d_in, const int* in_sizes, int n_in,
                              void* d_out, int out_size, void* d_ws, size_t ws_size,
                              hipStream_t stream) {
    const vf2*  spec  = (const vf2*)d_in[0];
    const vf2*  ftune = (const vf2*)d_in[1];
    const float* thr   = (const float*)d_in[2];
    const float* ratio = (const float*)d_in[3];
    vf2* out = (vf2*)d_out;

    const int total_threads = kB * kF2 * kNC;   // 262144
    dim3 grid(total_threads / 256), block(256);
    cochlea_kernel<<<grid, block, 0, stream>>>(spec, ftune, thr, ratio, out);
}

// Round 4
// 18.055 us; speedup vs baseline: 2.6049x; 1.3440x over previous
//
#include <hip/hip_runtime.h>

// Cochlea: per-f compress + first-order IIR (alpha=0.9) along T + ReLU.
// B=32, T=4096, F=64.
//
// Round-3 post-mortem: traffic-bound (rounds 2/3: 142MB@24.7us=5.7TB/s,
// 200MB@24.3us=8.2TB/s mixed HBM/L3). Lever: kill the 5x read amplification
// from per-thread warm-up.
//
// Design: block = 12 segments x 32 f2-lanes (384 thr). Each thread scans
// L=16 steps with y0=0 into registers + carry C. Segments 0..3 are shared
// warm-up (64 steps, alpha^64 ~ 1.2e-3 truncation); segments 4..11 are
// output. Carries combine exactly in-block via LDS + Horner with constant
// alpha^16; outputs fixed up as out[j] = relu(r[j] + alpha^(j+1) * y_in).
// Read amplification 1.5x instead of 5x. First T-block injects a virtual
// carry C=-1 = compressed[0] to reproduce the reference's y0 = c0 exactly.

typedef float vf2 __attribute__((ext_vector_type(2)));

namespace {
constexpr int kB    = 32;
constexpr int kT    = 4096;
constexpr int kF2   = 32;              // 64 floats = 32 vf2 per row
constexpr int kL    = 16;              // t-steps per segment
constexpr int kWSEG = 4;               // warm-up segments (64 steps)
constexpr int kOSEG = 8;               // output segments
constexpr int kSEG  = kWSEG + kOSEG;   // 12
constexpr int kTBLK = kOSEG * kL;      // 128 output steps per block
constexpr int kNTB  = kT / kTBLK;      // 32 T-blocks
constexpr float kA   = 0.9f;
constexpr float kOmA = 1.0f - kA;

constexpr float apow(int n) { float r = 1.f; for (int i = 0; i < n; ++i) r *= 0.9f; return r; }
constexpr float kA16 = apow(kL);       // alpha^16
}

__global__ __launch_bounds__(384) void cochlea_kernel(
    const vf2* __restrict__ spec,
    const vf2* __restrict__ ftune,
    const float* __restrict__ thr_p,
    const float* __restrict__ ratio_p,
    vf2* __restrict__ out)
{
    const int tid = threadIdx.x;
    const int f2  = tid & (kF2 - 1);
    const int seg = tid >> 5;                 // 0..11, wave-uniform pairs
    const int tb  = blockIdx.x & (kNTB - 1);
    const int b   = blockIdx.x >> 5;

    const float thr   = thr_p[0];
    const float ratio = ratio_p[0];
    const vf2 ft = ftune[f2];

    const int t0   = tb * kTBLK;              // block's first output t
    const int tseg = t0 + (seg - kWSEG) * kL; // this thread's first t
    const bool valid = tseg >= 0;             // false only for tb==0 warm-ups

    const size_t rowbase = (size_t)b * kT * kF2 + f2;
    const vf2* sp = spec + rowbase + (size_t)(valid ? tseg : 0) * kF2;

    vf2 y  = {0.f, 0.f};                      // running local scan / carry
    vf2 v0 = {0.f, 0.f};                      // first compressed value
    vf2 r[kL];                                // local scan results (regs)

    if (valid) {
        #pragma unroll
        for (int g = 0; g < kL / 8; ++g) {
            vf2 xv[8];
            #pragma unroll
            for (int j = 0; j < 8; ++j)
                xv[j] = sp[(size_t)(g * 8 + j) * kF2];
            #pragma unroll
            for (int j = 0; j < 8; ++j) {
                float ta = xv[j].x * ft.x;
                float tc = xv[j].y * ft.y;
                float ca = fmaf(ta - thr, ratio, thr);
                float cc = fmaf(tc - thr, ratio, thr);
                vf2 v;
                v.x = (ta > thr) ? ca : ta;
                v.y = (tc > thr) ? cc : tc;
                if (g == 0 && j == 0) v0 = v;
                y.x = fmaf(kA, y.x, kOmA * v.x);
                y.y = fmaf(kA, y.y, kOmA * v.y);
                r[g * 8 + j] = y;
            }
        }
    }

    __shared__ vf2 lds_c[kSEG][kF2];
    lds_c[seg][f2] = y;                       // segment carry (0 if invalid)
    __syncthreads();
    if (tb == 0) {                            // block-uniform branch
        // Virtual carry: y_in(first output seg) must equal compressed[t=0]
        // so the uniform recurrence reproduces y0 = c0 exactly.
        if (seg == kWSEG) lds_c[kWSEG - 1][f2] = v0;
        __syncthreads();
    }

    if (seg >= kWSEG) {
        // Exact in-block combine: yin = sum_{j<seg} A16^(seg-1-j) * C_j
        // via Horner with the single constant A16 (wave-uniform trip count).
        vf2 yin = {0.f, 0.f};
        for (int j = 0; j < seg; ++j) {
            vf2 c = lds_c[j][f2];
            yin.x = fmaf(kA16, yin.x, c.x);
            yin.y = fmaf(kA16, yin.y, c.y);
        }
        vf2* op = out + rowbase + (size_t)tseg * kF2;
        float ap = kA;                        // alpha^(j+1)
        #pragma unroll
        for (int j = 0; j < kL; ++j) {
            vf2 o;
            o.x = fmaxf(fmaf(ap, yin.x, r[j].x), 0.f);
            o.y = fmaxf(fmaf(ap, yin.y, r[j].y), 0.f);
            __builtin_nontemporal_store(o, op + (size_t)j * kF2);
            ap *= kA;
        }
    }
}

extern "C" void kernel_launch(void* const* d_in, const int* in_sizes, int n_in,
                              void* d_out, int out_size, void* d_ws, size_t ws_size,
                              hipStream_t stream) {
    const vf2*   spec  = (const vf2*)d_in[0];
    const vf2*   ftune = (const vf2*)d_in[1];
    const float* thr   = (const float*)d_in[2];
    const float* ratio = (const float*)d_in[3];
    vf2* out = (vf2*)d_out;

    dim3 grid(kB * kNTB), block(kSEG * kF2);  // 1024 blocks x 384 threads
    cochlea_kernel<<<grid, block, 0, stream>>>(spec, ftune, thr, ratio, out);
}

// Round 5
// 16.415 us; speedup vs baseline: 2.8652x; 1.0999x over previous
//
#include <hip/hip_runtime.h>

// Cochlea: per-f compress + first-order IIR (alpha=0.9) along T + ReLU.
// B=32, T=4096, F=64.
//
// Block = 20 segments x 32 f2-lanes (640 thr). Each thread scans L=16
// steps (y0=0) into registers + carry. Segments 0..3 are shared warm-up
// (64 steps, alpha^64 ~ 1.2e-3 truncation, threshold 2.78e-2); segments
// 4..19 produce output. Carries combine exactly in-block (LDS + Horner,
// constant alpha^16); fixup out[j] = relu(r[j] + alpha^(j+1) * y_in).
// Read amplification 20/16 = 1.25x (was 1.5x in round 4). First T-block
// injects virtual carry C = compressed[t=0] for exact y0 = c0 semantics.
//
// Round-4 post-mortem: 18.1us vs 12.7us traffic ideal at 84MB -> cut
// amplification (84->75MB) + stage all 16 loads up-front per thread.

typedef float vf2 __attribute__((ext_vector_type(2)));

namespace {
constexpr int kB    = 32;
constexpr int kT    = 4096;
constexpr int kF2   = 32;              // 64 floats = 32 vf2 per row
constexpr int kL    = 16;              // t-steps per segment
constexpr int kWSEG = 4;               // warm-up segments (64 steps)
constexpr int kOSEG = 16;              // output segments
constexpr int kSEG  = kWSEG + kOSEG;   // 20
constexpr int kTBLK = kOSEG * kL;      // 256 output steps per block
constexpr int kNTB  = kT / kTBLK;      // 16 T-blocks
constexpr float kA   = 0.9f;
constexpr float kOmA = 1.0f - kA;

constexpr float apow(int n) { float r = 1.f; for (int i = 0; i < n; ++i) r *= 0.9f; return r; }
constexpr float kA16 = apow(kL);       // alpha^16
}

__global__ __launch_bounds__(kSEG * kF2) void cochlea_kernel(
    const vf2* __restrict__ spec,
    const vf2* __restrict__ ftune,
    const float* __restrict__ thr_p,
    const float* __restrict__ ratio_p,
    vf2* __restrict__ out)
{
    const int tid = threadIdx.x;
    const int f2  = tid & (kF2 - 1);
    const int seg = tid >> 5;                 // 0..19
    const int tb  = blockIdx.x & (kNTB - 1);
    const int b   = blockIdx.x >> 4;

    const float thr   = thr_p[0];
    const float ratio = ratio_p[0];
    const vf2 ft = ftune[f2];

    const int t0   = tb * kTBLK;              // block's first output t
    const int tseg = t0 + (seg - kWSEG) * kL; // this thread's first t
    const bool valid = tseg >= 0;             // false only for tb==0 warm-ups

    const size_t rowbase = (size_t)b * kT * kF2 + f2;
    const vf2* sp = spec + rowbase + (size_t)(valid ? tseg : 0) * kF2;

    vf2 y  = {0.f, 0.f};                      // running local scan / carry
    vf2 v0 = {0.f, 0.f};                      // first compressed value
    vf2 r[kL];                                // local scan results (regs)

    if (valid) {
        vf2 xv[kL];                           // stage ALL 16 loads (128B/thr)
        #pragma unroll
        for (int j = 0; j < kL; ++j)
            xv[j] = sp[(size_t)j * kF2];
        #pragma unroll
        for (int j = 0; j < kL; ++j) {
            float ta = xv[j].x * ft.x;
            float tc = xv[j].y * ft.y;
            float ca = fmaf(ta - thr, ratio, thr);
            float cc = fmaf(tc - thr, ratio, thr);
            vf2 v;
            v.x = (ta > thr) ? ca : ta;
            v.y = (tc > thr) ? cc : tc;
            if (j == 0) v0 = v;
            y.x = fmaf(kA, y.x, kOmA * v.x);
            y.y = fmaf(kA, y.y, kOmA * v.y);
            r[j] = y;
        }
    }

    __shared__ vf2 lds_c[kSEG][kF2];
    lds_c[seg][f2] = y;                       // segment carry (0 if invalid)
    __syncthreads();
    if (tb == 0) {                            // block-uniform branch
        // Virtual carry: y_in(first output seg) = compressed[t=0] so the
        // uniform recurrence reproduces y0 = c0 exactly.
        if (seg == kWSEG) lds_c[kWSEG - 1][f2] = v0;
        __syncthreads();
    }

    if (seg >= kWSEG) {
        // Exact in-block combine: yin = sum_{j<seg} A16^(seg-1-j) * C_j.
        vf2 yin = {0.f, 0.f};
        for (int j = 0; j < seg; ++j) {
            vf2 c = lds_c[j][f2];
            yin.x = fmaf(kA16, yin.x, c.x);
            yin.y = fmaf(kA16, yin.y, c.y);
        }
        vf2* op = out + rowbase + (size_t)tseg * kF2;
        float ap = kA;                        // alpha^(j+1)
        #pragma unroll
        for (int j = 0; j < kL; ++j) {
            vf2 o;
            o.x = fmaxf(fmaf(ap, yin.x, r[j].x), 0.f);
            o.y = fmaxf(fmaf(ap, yin.y, r[j].y), 0.f);
            __builtin_nontemporal_store(o, op + (size_t)j * kF2);
            ap *= kA;
        }
    }
}

extern "C" void kernel_launch(void* const* d_in, const int* in_sizes, int n_in,
                              void* d_out, int out_size, void* d_ws, size_t ws_size,
                              hipStream_t stream) {
    const vf2*   spec  = (const vf2*)d_in[0];
    const vf2*   ftune = (const vf2*)d_in[1];
    const float* thr   = (const float*)d_in[2];
    const float* ratio = (const float*)d_in[3];
    vf2* out = (vf2*)d_out;

    dim3 grid(kB * kNTB), block(kSEG * kF2);  // 512 blocks x 640 threads
    cochlea_kernel<<<grid, block, 0, stream>>>(spec, ftune, thr, ratio, out);
}